// Round 1
// baseline (411.393 us; speedup 1.0000x reference)
//
#include <hip/hip_runtime.h>
#include <hip/hip_bf16.h>
#include <math.h>

#define M 4096
#define PWR 128            // packed words per row = 4096/32
#define ALPHA 0.2f

// ---------------- pack adj (int32 -> bitmask) ----------------
__global__ __launch_bounds__(256) void pack_adj_kernel(const int* __restrict__ adj,
                                                       unsigned int* __restrict__ packed) {
    int idx = blockIdx.x * 256 + threadIdx.x;           // covers M*M exactly
    int val = adj[idx] > 0 ? 1 : 0;
    unsigned long long mask = __ballot(val);
    int lane = threadIdx.x & 63;
    unsigned long long wid = ((unsigned long long)idx) >> 6;
    if (lane == 0)  packed[wid * 2]     = (unsigned int)(mask & 0xffffffffull);
    if (lane == 32) packed[wid * 2 + 1] = (unsigned int)(mask >> 32);
}

// ---------------- tiny GEMM: Y[M][DOUT] = X[M][DIN] @ W[DIN][DOUT] ----------------
template <int DIN, int DOUT>
__global__ __launch_bounds__(256) void gemm_kernel(const float* __restrict__ X,
                                                   const float* __restrict__ W,
                                                   float* __restrict__ Y) {
    int tid = blockIdx.x * 256 + threadIdx.x;
    int i = tid / DOUT, f = tid % DOUT;
    if (i >= M) return;
    float acc = 0.f;
#pragma unroll
    for (int j = 0; j < DIN; j++) acc += X[i * DIN + j] * W[j * DOUT + f];
    Y[i * DOUT + f] = acc;
}

// ---------------- s_i / s_k per row: dot(Wh[i], a[:F]) and dot(Wh[i], a[F:]) ----------------
template <int F>
__global__ __launch_bounds__(64) void svec_kernel(const float* __restrict__ Wh,
                                                  const float* __restrict__ a,
                                                  float* __restrict__ s_i,
                                                  float* __restrict__ s_k) {
    int i = blockIdx.x;
    int lane = threadIdx.x;                              // 0..63
    float w  = (lane < F) ? Wh[i * F + lane] : 0.f;
    float ai = (lane < F) ? a[lane] : 0.f;
    float ak = (lane < F) ? a[F + lane] : 0.f;
    float vi = w * ai, vk = w * ak;
#pragma unroll
    for (int off = 32; off; off >>= 1) {
        vi += __shfl_down(vi, off);
        vk += __shfl_down(vk, off);
    }
    if (lane == 0) { s_i[i] = vi; s_k[i] = vk; }
}

// ---------------- per-row softmax stats: rowmax, 1/rowsum ----------------
__global__ __launch_bounds__(256) void row_stats_kernel(const float* __restrict__ s_i,
                                                        const float* __restrict__ s_k,
                                                        const unsigned int* __restrict__ packed,
                                                        float* __restrict__ rowmax,
                                                        float* __restrict__ rowinv) {
    __shared__ float sk_lds[M];                          // 16 KB
    int tid = threadIdx.x;
    for (int j = tid; j < M; j += 256) sk_lds[j] = s_k[j];
    __syncthreads();
    int wave = tid >> 6, lane = tid & 63;
    int i = blockIdx.x * 4 + wave;
    float si = s_i[i];
    const unsigned int* prow = packed + (size_t)i * PWR;
    // pass 1: max over unmasked
    float m = -INFINITY;
    for (int k = lane; k < M; k += 64) {
        unsigned int bit = (prow[k >> 5] >> (k & 31)) & 1u;
        if (bit) {
            float x = si + sk_lds[k];
            float e = x > 0.f ? x : ALPHA * x;
            m = fmaxf(m, e);
        }
    }
#pragma unroll
    for (int off = 32; off; off >>= 1) m = fmaxf(m, __shfl_xor(m, off));
    // pass 2: sum of exp(e - max)
    float s = 0.f;
    for (int k = lane; k < M; k += 64) {
        unsigned int bit = (prow[k >> 5] >> (k & 31)) & 1u;
        if (bit) {
            float x = si + sk_lds[k];
            float e = x > 0.f ? x : ALPHA * x;
            s += __expf(e - m);
        }
    }
#pragma unroll
    for (int off = 32; off; off >>= 1) s += __shfl_xor(s, off);
    if (lane == 0) {
        rowmax[i] = m;
        rowinv[i] = (s > 0.f) ? 1.f / s : 0.f;
    }
}

// ---------------- fused attention @ Wh with ELU epilogue ----------------
// Block: 256 threads. f = tid % F lane-feature; RG = 256/F row-groups; RT rows/thread.
// Per k-chunk (KC=64): stage Wh^T chunk + att-weights chunk into LDS, then FMA.
template <int F, int RT, int RG>
__global__ __launch_bounds__(256) void attn_av_kernel(const float* __restrict__ Wh,
                                                      const float* __restrict__ s_i,
                                                      const float* __restrict__ s_k,
                                                      const float* __restrict__ rowmax,
                                                      const float* __restrict__ rowinv,
                                                      const unsigned int* __restrict__ packed,
                                                      float* __restrict__ hout,
                                                      float* __restrict__ hout2) {
    constexpr int R = RG * RT;          // rows per block
    constexpr int KC = 64;
    constexpr int KS = KC + 4;          // 68 floats = 17 x 16B -> conflict-free b128
    __shared__ __align__(16) float whT[F][KS];
    __shared__ __align__(16) float wlds[R][KS];

    int tid = threadIdx.x;
    int f = tid % F;
    int rg = tid / F;                   // 0..RG-1
    int row0 = blockIdx.x * R;
    float acc[RT];
#pragma unroll
    for (int t = 0; t < RT; t++) acc[t] = 0.f;

    for (int kc = 0; kc < M; kc += KC) {
        __syncthreads();
        // stage Wh^T: whT[f][kk] = Wh[kc+kk][f]
        for (int kk = rg; kk < KC; kk += RG)
            whT[f][kk] = Wh[(size_t)(kc + kk) * F + f];
        // stage attention weights w[r][kk]
        for (int l = tid; l < R * KC; l += 256) {
            int r = l / KC, kk = l % KC;
            int i = row0 + r, k = kc + kk;
            unsigned int bit = (packed[(size_t)i * PWR + (k >> 5)] >> (k & 31)) & 1u;
            float wv = 0.f;
            if (bit) {
                float x = s_i[i] + s_k[k];
                float e = x > 0.f ? x : ALPHA * x;
                wv = __expf(e - rowmax[i]) * rowinv[i];
            }
            wlds[r][kk] = wv;
        }
        __syncthreads();
        // MAC
        for (int kk = 0; kk < KC; kk += 4) {
            float4 wh = *(const float4*)&whT[f][kk];
#pragma unroll
            for (int t = 0; t < RT; t++) {
                int r = rg * RT + t;
                float4 wv = *(const float4*)&wlds[r][kk];
                acc[t] += wv.x * wh.x + wv.y * wh.y + wv.z * wh.z + wv.w * wh.w;
            }
        }
    }
    // epilogue: ELU, store
#pragma unroll
    for (int t = 0; t < RT; t++) {
        int i = row0 + rg * RT + t;
        float v = acc[t];
        v = v > 0.f ? v : (__expf(v) - 1.f);
        hout[(size_t)i * F + f] = v;
        if (hout2) hout2[(size_t)i * F + f] = v;
    }
}

// ---------------- final pairwise sigmoid ----------------
__global__ __launch_bounds__(256) void pred_kernel(const float* __restrict__ p_i,
                                                   const float* __restrict__ p_k,
                                                   float* __restrict__ out) {
    int tid = blockIdx.x * 256 + threadIdx.x;            // over M*M/4
    int i = tid / (M / 4);
    int k4 = (tid % (M / 4)) * 4;
    float pi = p_i[i];
    float4 pk = *(const float4*)&p_k[k4];
    float4 o;
    o.x = 1.f / (1.f + __expf(-(pi + pk.x)));
    o.y = 1.f / (1.f + __expf(-(pi + pk.y)));
    o.z = 1.f / (1.f + __expf(-(pi + pk.z)));
    o.w = 1.f / (1.f + __expf(-(pi + pk.w)));
    *(float4*)&out[(size_t)i * M + k4] = o;
}

extern "C" void kernel_launch(void* const* d_in, const int* in_sizes, int n_in,
                              void* d_out, int out_size, void* d_ws, size_t ws_size,
                              hipStream_t stream) {
    const float* h0    = (const float*)d_in[0];
    const int*   adj   = (const int*)d_in[1];
    const float* W1    = (const float*)d_in[2];
    const float* a1    = (const float*)d_in[3];
    const float* W2    = (const float*)d_in[4];
    const float* a2    = (const float*)d_in[5];
    const float* omega = (const float*)d_in[6];
    float* out = (float*)d_out;

    char* ws = (char*)d_ws;
    unsigned int* packed = (unsigned int*)(ws + 0);       // 2 MB
    float* Wh1 = (float*)(ws + 2097152);                  // 1 MB
    float* h1  = (float*)(ws + 3145728);                  // 1 MB
    float* Wh2 = (float*)(ws + 4194304);                  // 512 KB
    float* hL  = (float*)(ws + 4718592);                  // 512 KB
    float* si1 = (float*)(ws + 5242880);
    float* sk1 = (float*)(ws + 5259264);
    float* mx1 = (float*)(ws + 5275648);
    float* iv1 = (float*)(ws + 5292032);
    float* si2 = (float*)(ws + 5308416);
    float* sk2 = (float*)(ws + 5324800);
    float* mx2 = (float*)(ws + 5341184);
    float* iv2 = (float*)(ws + 5357568);
    float* pi  = (float*)(ws + 5373952);
    float* pk  = (float*)(ws + 5390336);

    // 1. pack mask
    pack_adj_kernel<<<(M * M) / 256, 256, 0, stream>>>(adj, packed);
    // 2-5. layer 1 (F=64)
    gemm_kernel<64, 64><<<(M * 64) / 256, 256, 0, stream>>>(h0, W1, Wh1);
    svec_kernel<64><<<M, 64, 0, stream>>>(Wh1, a1, si1, sk1);
    row_stats_kernel<<<M / 4, 256, 0, stream>>>(si1, sk1, packed, mx1, iv1);
    attn_av_kernel<64, 2, 4><<<M / 8, 256, 0, stream>>>(Wh1, si1, sk1, mx1, iv1, packed, h1, nullptr);
    // 6-9. layer 2 (F=32), hL also written to d_out tail
    gemm_kernel<64, 32><<<(M * 32) / 256, 256, 0, stream>>>(h1, W2, Wh2);
    svec_kernel<32><<<M, 64, 0, stream>>>(Wh2, a2, si2, sk2);
    row_stats_kernel<<<M / 4, 256, 0, stream>>>(si2, sk2, packed, mx2, iv2);
    attn_av_kernel<32, 2, 8><<<M / 16, 256, 0, stream>>>(Wh2, si2, sk2, mx2, iv2, packed,
                                                         hL, out + (size_t)M * M);
    // 10-11. link prediction
    svec_kernel<32><<<M, 64, 0, stream>>>(hL, omega, pi, pk);
    pred_kernel<<<(M * M / 4) / 256, 256, 0, stream>>>(pi, pk, out);
}

// Round 3
// 188.296 us; speedup vs baseline: 2.1848x; 2.1848x over previous
//
#include <hip/hip_runtime.h>
#include <hip/hip_bf16.h>
#include <math.h>

#define M 4096
#define PWR 128            // packed words per row = 4096/32
#define ALPHA 0.2f

// ---------------- pack adj (int32 -> bitmask) ----------------
__global__ __launch_bounds__(256) void pack_adj_kernel(const int* __restrict__ adj,
                                                       unsigned int* __restrict__ packed) {
    int idx = blockIdx.x * 256 + threadIdx.x;           // covers M*M exactly
    int val = adj[idx] > 0 ? 1 : 0;
    unsigned long long mask = __ballot(val);
    int lane = threadIdx.x & 63;
    unsigned long long wid = ((unsigned long long)idx) >> 6;
    if (lane == 0)  packed[wid * 2]     = (unsigned int)(mask & 0xffffffffull);
    if (lane == 32) packed[wid * 2 + 1] = (unsigned int)(mask >> 32);
}

// ---------------- tiny GEMM: Y[M][DOUT] = X[M][DIN] @ W[DIN][DOUT] ----------------
template <int DIN, int DOUT>
__global__ __launch_bounds__(256) void gemm_kernel(const float* __restrict__ X,
                                                   const float* __restrict__ W,
                                                   float* __restrict__ Y) {
    int tid = blockIdx.x * 256 + threadIdx.x;
    int i = tid / DOUT, f = tid % DOUT;
    if (i >= M) return;
    float acc = 0.f;
#pragma unroll
    for (int j = 0; j < DIN; j++) acc += X[i * DIN + j] * W[j * DOUT + f];
    Y[i * DOUT + f] = acc;
}

// ---------------- s_i / s_k per row ----------------
template <int F>
__global__ __launch_bounds__(64) void svec_kernel(const float* __restrict__ Wh,
                                                  const float* __restrict__ a,
                                                  float* __restrict__ s_i,
                                                  float* __restrict__ s_k) {
    int i = blockIdx.x;
    int lane = threadIdx.x;                              // 0..63
    float w  = (lane < F) ? Wh[i * F + lane] : 0.f;
    float ai = (lane < F) ? a[lane] : 0.f;
    float ak = (lane < F) ? a[F + lane] : 0.f;
    float vi = w * ai, vk = w * ak;
#pragma unroll
    for (int off = 32; off; off >>= 1) {
        vi += __shfl_down(vi, off);
        vk += __shfl_down(vk, off);
    }
    if (lane == 0) { s_i[i] = vi; s_k[i] = vk; }
}

// ---------------- per-row softmax stats ----------------
__global__ __launch_bounds__(256) void row_stats_kernel(const float* __restrict__ s_i,
                                                        const float* __restrict__ s_k,
                                                        const unsigned int* __restrict__ packed,
                                                        float* __restrict__ rowmax,
                                                        float* __restrict__ rowinv) {
    __shared__ float sk_lds[M];                          // 16 KB
    int tid = threadIdx.x;
    for (int j = tid; j < M; j += 256) sk_lds[j] = s_k[j];
    __syncthreads();
    int wave = tid >> 6, lane = tid & 63;
    int i = blockIdx.x * 4 + wave;
    float si = s_i[i];
    const unsigned int* prow = packed + (size_t)i * PWR;
    float m = -INFINITY;
    for (int k = lane; k < M; k += 64) {
        unsigned int bit = (prow[k >> 5] >> (k & 31)) & 1u;
        if (bit) {
            float x = si + sk_lds[k];
            float e = x > 0.f ? x : ALPHA * x;
            m = fmaxf(m, e);
        }
    }
#pragma unroll
    for (int off = 32; off; off >>= 1) m = fmaxf(m, __shfl_xor(m, off));
    float s = 0.f;
    for (int k = lane; k < M; k += 64) {
        unsigned int bit = (prow[k >> 5] >> (k & 31)) & 1u;
        if (bit) {
            float x = si + sk_lds[k];
            float e = x > 0.f ? x : ALPHA * x;
            s += __expf(e - m);
        }
    }
#pragma unroll
    for (int off = 32; off; off >>= 1) s += __shfl_xor(s, off);
    if (lane == 0) {
        rowmax[i] = m;
        rowinv[i] = (s > 0.f) ? 1.f / s : 0.f;
    }
}

// ---------------- split-K attention @ Wh, outer-product register tiling ----------------
// Block = 256 threads. TF=8 features/thread, TR rows/thread.
// FQ = F/8 feature groups, RQ = 256/FQ row groups, RB = RQ*TR rows/block (must be 256).
// KSPLIT blocks cover disjoint K ranges; partial[ks][i][f] accumulated, reduced later.
template <int F, int TR, int KSPLIT>
__global__ __launch_bounds__(256) void attn_av_kernel(const float* __restrict__ Wh,
                                                      const float* __restrict__ s_i,
                                                      const float* __restrict__ s_k,
                                                      const float* __restrict__ rowmax,
                                                      const float* __restrict__ rowinv,
                                                      const unsigned int* __restrict__ packed,
                                                      float* __restrict__ partial) {
    constexpr int TF = 8;
    constexpr int FQ = F / TF;            // 8 (F=64) or 4 (F=32)
    constexpr int RQ = 256 / FQ;          // 32 or 64
    constexpr int RB = RQ * TR;           // 256 rows per block
    static_assert(RB == 256, "staging assumes RB==256");
    constexpr int KC = 32;                // k-chunk (one packed word)
    constexpr int KLEN = M / KSPLIT;
    constexpr int NRB = M / RB;           // row-blocks

    __shared__ __align__(16) float wh_lds[KC][F];     // 8 KB / 4 KB
    __shared__ __align__(16) float wt_lds[KC][RB];    // 32 KB

    int tid = threadIdx.x;
    int fq = tid % FQ;
    int rq = tid / FQ;
    int rb0 = (blockIdx.x % NRB) * RB;
    int ks  = blockIdx.x / NRB;
    int k0  = ks * KLEN;

    // staging: this thread owns row (rb0 + tid) for weight computation
    int i_st = rb0 + tid;
    float si  = s_i[i_st];
    float rmx = rowmax[i_st];
    float rin = rowinv[i_st];
    const unsigned int* prow = packed + (size_t)i_st * PWR + (k0 >> 5);

    float acc[TR][TF];
#pragma unroll
    for (int t = 0; t < TR; t++)
#pragma unroll
        for (int j = 0; j < TF; j++) acc[t][j] = 0.f;

    for (int kc = 0; kc < KLEN; kc += KC) {
        __syncthreads();
        // ---- stage Wh chunk (coalesced float4) ----
        constexpr int WHL = (KC * F) / (256 * 4);     // 2 or 1
#pragma unroll
        for (int t = 0; t < WHL; t++) {
            int l = tid + t * 256;                    // float4 index
            int kk = l / (F / 4);
            int ff = (l % (F / 4)) * 4;
            *(float4*)&wh_lds[kk][ff] =
                *(const float4*)&Wh[(size_t)(k0 + kc + kk) * F + ff];
        }
        // ---- stage weights: one packed word covers this chunk's 32 bits ----
        unsigned int word = prow[kc >> 5];
#pragma unroll
        for (int kk = 0; kk < KC; kk++) {
            float x = si + s_k[k0 + kc + kk];
            float e = x > 0.f ? x : ALPHA * x;
            float wv = ((word >> kk) & 1u) ? __expf(e - rmx) * rin : 0.f;
            wt_lds[kk][tid] = wv;
        }
        __syncthreads();
        // ---- MAC: outer product ----
#pragma unroll 4
        for (int kk = 0; kk < KC; kk++) {
            float wh[TF];
            float4 wa = *(const float4*)&wh_lds[kk][fq * TF];
            float4 wb = *(const float4*)&wh_lds[kk][fq * TF + 4];
            wh[0] = wa.x; wh[1] = wa.y; wh[2] = wa.z; wh[3] = wa.w;
            wh[4] = wb.x; wh[5] = wb.y; wh[6] = wb.z; wh[7] = wb.w;
            float wt[TR];
            float4 ta = *(const float4*)&wt_lds[kk][rq * TR];
            wt[0] = ta.x; wt[1] = ta.y; wt[2] = ta.z; wt[3] = ta.w;
            if (TR == 8) {
                float4 tb = *(const float4*)&wt_lds[kk][rq * TR + 4];
                wt[4] = tb.x; wt[5] = tb.y; wt[6] = tb.z; wt[7] = tb.w;
            }
#pragma unroll
            for (int t = 0; t < TR; t++)
#pragma unroll
                for (int j = 0; j < TF; j++)
                    acc[t][j] += wt[t] * wh[j];
        }
    }
    // ---- store partials ----
#pragma unroll
    for (int t = 0; t < TR; t++) {
        size_t base = ((size_t)ks * M + rb0 + rq * TR + t) * F + fq * TF;
        float4 oa = { acc[t][0], acc[t][1], acc[t][2], acc[t][3] };
        float4 ob = { acc[t][4], acc[t][5], acc[t][6], acc[t][7] };
        *(float4*)&partial[base]     = oa;
        *(float4*)&partial[base + 4] = ob;
    }
}

// ---------------- reduce partials + ELU ----------------
template <int F, int KSPLIT>
__global__ __launch_bounds__(256) void reduce_elu_kernel(const float* __restrict__ partial,
                                                         float* __restrict__ hout,
                                                         float* __restrict__ hout2) {
    int idx4 = blockIdx.x * 256 + threadIdx.x;        // over M*F/4
    size_t off = (size_t)idx4 * 4;
    float4 s = { 0.f, 0.f, 0.f, 0.f };
#pragma unroll
    for (int ks = 0; ks < KSPLIT; ks++) {
        float4 p = *(const float4*)&partial[(size_t)ks * M * F + off];
        s.x += p.x; s.y += p.y; s.z += p.z; s.w += p.w;
    }
    s.x = s.x > 0.f ? s.x : (__expf(s.x) - 1.f);
    s.y = s.y > 0.f ? s.y : (__expf(s.y) - 1.f);
    s.z = s.z > 0.f ? s.z : (__expf(s.z) - 1.f);
    s.w = s.w > 0.f ? s.w : (__expf(s.w) - 1.f);
    *(float4*)&hout[off] = s;
    if (hout2) *(float4*)&hout2[off] = s;
}

// ---------------- final pairwise sigmoid ----------------
__global__ __launch_bounds__(256) void pred_kernel(const float* __restrict__ p_i,
                                                   const float* __restrict__ p_k,
                                                   float* __restrict__ out) {
    int tid = blockIdx.x * 256 + threadIdx.x;            // over M*M/4
    int i = tid / (M / 4);
    int k4 = (tid % (M / 4)) * 4;
    float pi = p_i[i];
    float4 pk = *(const float4*)&p_k[k4];
    float4 o;
    o.x = 1.f / (1.f + __expf(-(pi + pk.x)));
    o.y = 1.f / (1.f + __expf(-(pi + pk.y)));
    o.z = 1.f / (1.f + __expf(-(pi + pk.z)));
    o.w = 1.f / (1.f + __expf(-(pi + pk.w)));
    *(float4*)&out[(size_t)i * M + k4] = o;
}

extern "C" void kernel_launch(void* const* d_in, const int* in_sizes, int n_in,
                              void* d_out, int out_size, void* d_ws, size_t ws_size,
                              hipStream_t stream) {
    const float* h0    = (const float*)d_in[0];
    const int*   adj   = (const int*)d_in[1];
    const float* W1    = (const float*)d_in[2];
    const float* a1    = (const float*)d_in[3];
    const float* W2    = (const float*)d_in[4];
    const float* a2    = (const float*)d_in[5];
    const float* omega = (const float*)d_in[6];
    float* out = (float*)d_out;

    char* ws = (char*)d_ws;
    unsigned int* packed = (unsigned int*)(ws + 0);       // 2 MB
    float* Wh1 = (float*)(ws + 2097152);                  // 1 MB
    float* h1  = (float*)(ws + 3145728);                  // 1 MB
    float* Wh2 = (float*)(ws + 4194304);                  // 512 KB
    float* hL  = (float*)(ws + 4718592);                  // 512 KB
    float* si1 = (float*)(ws + 5242880);
    float* sk1 = (float*)(ws + 5259264);
    float* mx1 = (float*)(ws + 5275648);
    float* iv1 = (float*)(ws + 5292032);
    float* si2 = (float*)(ws + 5308416);
    float* sk2 = (float*)(ws + 5324800);
    float* mx2 = (float*)(ws + 5341184);
    float* iv2 = (float*)(ws + 5357568);
    float* pi  = (float*)(ws + 5373952);
    float* pk  = (float*)(ws + 5390336);

    // d_out doubles as partial-sum scratch (overwritten by pred at the end)
    float* partial = out;                                  // layer1: 32 MB, layer2: 16 MB

    // 1. pack mask
    pack_adj_kernel<<<(M * M) / 256, 256, 0, stream>>>(adj, packed);

    // ---- layer 1 (F=64): TR=8, KSPLIT=32 -> 16*32=512 blocks ----
    gemm_kernel<64, 64><<<(M * 64) / 256, 256, 0, stream>>>(h0, W1, Wh1);
    svec_kernel<64><<<M, 64, 0, stream>>>(Wh1, a1, si1, sk1);
    row_stats_kernel<<<M / 4, 256, 0, stream>>>(si1, sk1, packed, mx1, iv1);
    attn_av_kernel<64, 8, 32><<<512, 256, 0, stream>>>(Wh1, si1, sk1, mx1, iv1, packed, partial);
    reduce_elu_kernel<64, 32><<<(M * 64 / 4) / 256, 256, 0, stream>>>(partial, h1, nullptr);

    // ---- layer 2 (F=32): TR=4, KSPLIT=32 -> 512 blocks ----
    gemm_kernel<64, 32><<<(M * 32) / 256, 256, 0, stream>>>(h1, W2, Wh2);
    svec_kernel<32><<<M, 64, 0, stream>>>(Wh2, a2, si2, sk2);
    row_stats_kernel<<<M / 4, 256, 0, stream>>>(si2, sk2, packed, mx2, iv2);
    attn_av_kernel<32, 4, 32><<<512, 256, 0, stream>>>(Wh2, si2, sk2, mx2, iv2, packed, partial);
    reduce_elu_kernel<32, 32><<<(M * 32 / 4) / 256, 256, 0, stream>>>(partial, hL,
                                                                     out + (size_t)M * M);

    // ---- link prediction ----
    svec_kernel<32><<<M, 64, 0, stream>>>(hL, omega, pi, pk);
    pred_kernel<<<(M * M / 4) / 256, 256, 0, stream>>>(pi, pk, out);
}

// Round 4
// 110.890 us; speedup vs baseline: 3.7099x; 1.6980x over previous
//
#include <hip/hip_runtime.h>
#include <hip/hip_bf16.h>
#include <math.h>

#define M 4096
#define PWR 128            // packed words per row = 4096/32
#define ALPHA 0.2f

typedef __attribute__((ext_vector_type(8))) short bf16x8_t;   // 8 bf16 = 4 VGPRs
typedef __attribute__((ext_vector_type(4))) float f32x4_t;    // MFMA accumulator

// round-to-nearest-even float -> bf16 bits (no header-API dependence)
__device__ inline unsigned short f2bf(float f) {
    unsigned int u = __float_as_uint(f);
    u = (u + 0x7fffu + ((u >> 16) & 1u)) >> 16;
    return (unsigned short)u;
}

// ---------------- pack adj (int32 -> bitmask) ----------------
__global__ __launch_bounds__(256) void pack_adj_kernel(const int* __restrict__ adj,
                                                       unsigned int* __restrict__ packed) {
    int idx = blockIdx.x * 256 + threadIdx.x;
    int val = adj[idx] > 0 ? 1 : 0;
    unsigned long long mask = __ballot(val);
    int lane = threadIdx.x & 63;
    unsigned long long wid = ((unsigned long long)idx) >> 6;
    if (lane == 0)  packed[wid * 2]     = (unsigned int)(mask & 0xffffffffull);
    if (lane == 32) packed[wid * 2 + 1] = (unsigned int)(mask >> 32);
}

// ---------------- fused: Wh1 = h0@W1 (registers), emit WhB1(bf16 frag layout), s_i, s_k ----
// one wave per row; block = 4 rows
template <int DIN, int F>
__global__ __launch_bounds__(256) void fused_in_kernel(const float* __restrict__ h0,
                                                       const float* __restrict__ W,
                                                       const float* __restrict__ a,
                                                       unsigned short* __restrict__ WhB,
                                                       float* __restrict__ s_i,
                                                       float* __restrict__ s_k) {
    int wave = threadIdx.x >> 6, lane = threadIdx.x & 63;
    int i = blockIdx.x * 4 + wave;
    float acc = 0.f;                                   // Wh[i][lane]
#pragma unroll
    for (int j = 0; j < DIN; j++)
        acc += h0[(size_t)i * DIN + j] * W[j * F + lane];
    float vi = acc * a[lane], vk = acc * a[F + lane];
#pragma unroll
    for (int off = 32; off; off >>= 1) { vi += __shfl_xor(vi, off); vk += __shfl_xor(vk, off); }
    if (lane == 0) { s_i[i] = vi; s_k[i] = vk; }
    // scatter into B-fragment layout: [k5][fblk][lane(=kg*16+fl)][j]
    constexpr int NFB = F / 16;
    int fb = lane >> 4, fl = lane & 15;
    size_t idx = (((size_t)(i >> 5) * NFB + fb) * 64 + (((i & 31) >> 3) * 16 + fl)) * 8 + (i & 7);
    WhB[idx] = f2bf(acc);
}

// ---------------- per-row softmax denom (single pass; rmx = leaky(si+skmax) bound) ----
__global__ __launch_bounds__(256) void rowsum_kernel(const float* __restrict__ s_i,
                                                     const float* __restrict__ s_k,
                                                     const unsigned int* __restrict__ packed,
                                                     float* __restrict__ crow) {
    __shared__ float sk_lds[M];                        // 16 KB
    __shared__ float wred[4];
    int tid = threadIdx.x;
    float lm = -INFINITY;
    for (int j = tid; j < M; j += 256) { float v = s_k[j]; sk_lds[j] = v; lm = fmaxf(lm, v); }
#pragma unroll
    for (int off = 32; off; off >>= 1) lm = fmaxf(lm, __shfl_xor(lm, off));
    if ((tid & 63) == 0) wred[tid >> 6] = lm;
    __syncthreads();
    float skmax = fmaxf(fmaxf(wred[0], wred[1]), fmaxf(wred[2], wred[3]));
    int wave = tid >> 6, lane = tid & 63;
    int i = blockIdx.x * 4 + wave;
    float si = s_i[i];
    float xm = si + skmax;
    float rmx = fmaxf(xm, ALPHA * xm);                 // >= true row max (leaky monotone)
    const unsigned int* prow = packed + (size_t)i * PWR;
    float sum = 0.f;
    for (int t = 0; t < M / 64; t++) {
        int k = lane + 64 * t;
        unsigned int bit = (prow[k >> 5] >> (k & 31)) & 1u;
        float x = si + sk_lds[k];
        float e = fmaxf(x, ALPHA * x);
        float p = __expf(e - rmx);
        sum += bit ? p : 0.f;
    }
#pragma unroll
    for (int off = 32; off; off >>= 1) sum += __shfl_xor(sum, off);
    if (lane == 0) crow[i] = -rmx - __logf(sum);       // P = exp(leaky + crow)
}

// ---------------- MFMA attention @ Wh: P generated in A-fragment registers ----------------
// block = 4 waves; wave owns 16 rows x F cols over KLEN; split-K partials
template <int F, int KSPLIT>
__global__ __launch_bounds__(256) void attn_mfma_kernel(const unsigned short* __restrict__ WhB,
                                                        const float* __restrict__ s_i,
                                                        const float* __restrict__ crow,
                                                        const unsigned int* __restrict__ packed,
                                                        const float* __restrict__ s_k,
                                                        float* __restrict__ partial) {
    constexpr int NFB = F / 16;
    constexpr int KLEN = M / KSPLIT;
    constexpr int NRB = M / 64;
    int wave = threadIdx.x >> 6, lane = threadIdx.x & 63;
    int rb = blockIdx.x % NRB, ks = blockIdx.x / NRB;
    int R0 = rb * 64 + wave * 16;
    int row = R0 + (lane & 15);                        // A-operand row for this lane
    int kg = lane >> 4;                                // k-group 0..3
    float si = s_i[row], cr = crow[row];
    f32x4_t acc[NFB];
#pragma unroll
    for (int fb = 0; fb < NFB; fb++) acc[fb] = (f32x4_t)0.f;
    const int k_begin = ks * KLEN;
    for (int st = 0; st < KLEN / 32; st++) {
        int kb = k_begin + st * 32;
        float4 sa = *(const float4*)&s_k[kb + kg * 8];
        float4 sb = *(const float4*)&s_k[kb + kg * 8 + 4];
        unsigned int word = packed[(size_t)row * PWR + (kb >> 5)];
        float sv[8] = { sa.x, sa.y, sa.z, sa.w, sb.x, sb.y, sb.z, sb.w };
        union { bf16x8_t v; unsigned short u[8]; } af;
#pragma unroll
        for (int j = 0; j < 8; j++) {
            float x = si + sv[j];
            float e = fmaxf(x, ALPHA * x);             // leakyrelu
            float p = __expf(e + cr);                  // exp(e - rmx) * rinv
            p = ((word >> (kg * 8 + j)) & 1u) ? p : 0.f;
            af.u[j] = f2bf(p);
        }
        const unsigned short* bp = WhB + (size_t)(kb >> 5) * (NFB * 512) + (size_t)lane * 8;
#pragma unroll
        for (int fb = 0; fb < NFB; fb++) {
            bf16x8_t bfrag = *(const bf16x8_t*)(bp + (size_t)fb * 512);
            acc[fb] = __builtin_amdgcn_mfma_f32_16x16x32_bf16(af.v, bfrag, acc[fb], 0, 0, 0);
        }
    }
    // D layout: col = lane&15, row = (lane>>4)*4 + r
#pragma unroll
    for (int fb = 0; fb < NFB; fb++)
#pragma unroll
        for (int r = 0; r < 4; r++) {
            int ro = R0 + kg * 4 + r;
            partial[((size_t)ks * M + ro) * F + fb * 16 + (lane & 15)] = acc[fb][r];
        }
}

// ---------------- fused: reduce partial1 -> h1 (ELU, regs) -> Wh2, WhB2, s_i2, s_k2 ----
template <int KSPLIT>
__global__ __launch_bounds__(256) void fused_mid_kernel(const float* __restrict__ partial,
                                                        const float* __restrict__ W2,
                                                        const float* __restrict__ a2,
                                                        unsigned short* __restrict__ WhB2,
                                                        float* __restrict__ s_i2,
                                                        float* __restrict__ s_k2) {
    __shared__ float h_lds[4][64];
    int wave = threadIdx.x >> 6, lane = threadIdx.x & 63;
    int i = blockIdx.x * 4 + wave;
    float hv = 0.f;
#pragma unroll
    for (int ks = 0; ks < KSPLIT; ks++) hv += partial[((size_t)ks * M + i) * 64 + lane];
    hv = hv > 0.f ? hv : (__expf(hv) - 1.f);           // ELU -> h1[i][lane]
    h_lds[wave][lane] = hv;
    __syncthreads();
    int g = lane & 31, half = lane >> 5;
    float w2acc = 0.f;                                 // Wh2[i][g], split f-range by half
#pragma unroll
    for (int f = 0; f < 32; f++) {
        float hf = h_lds[wave][half * 32 + f];
        w2acc += hf * W2[(half * 32 + f) * 32 + g];
    }
    w2acc += __shfl_xor(w2acc, 32);
    float vi = w2acc * a2[g], vk = w2acc * a2[32 + g];
#pragma unroll
    for (int off = 16; off; off >>= 1) { vi += __shfl_xor(vi, off); vk += __shfl_xor(vk, off); }
    if (lane == 0) { s_i2[i] = vi; s_k2[i] = vk; }
    if (half == 0) {
        size_t idx = (((size_t)(i >> 5) * 2 + (g >> 4)) * 64 + (((i & 31) >> 3) * 16 + (g & 15))) * 8 + (i & 7);
        WhB2[idx] = f2bf(w2acc);
    }
}

// ---------------- fused: reduce partial2 -> hL (ELU) -> out tail + omega dots ----------------
template <int KSPLIT>
__global__ __launch_bounds__(256) void fused_out_kernel(const float* __restrict__ partial,
                                                        const float* __restrict__ omega,
                                                        float* __restrict__ hL_out,
                                                        float* __restrict__ p_i,
                                                        float* __restrict__ p_k) {
    int wave = threadIdx.x >> 6, lane = threadIdx.x & 63;
    int i = blockIdx.x * 4 + wave;
    int g = lane & 31, half = lane >> 5;
    float hv = 0.f;
#pragma unroll
    for (int h = 0; h < KSPLIT / 2; h++) {
        int ks = half * (KSPLIT / 2) + h;
        hv += partial[((size_t)ks * M + i) * 32 + g];
    }
    hv += __shfl_xor(hv, 32);
    hv = hv > 0.f ? hv : (__expf(hv) - 1.f);
    if (half == 0) hL_out[(size_t)i * 32 + g] = hv;
    float vi = hv * omega[g], vk = hv * omega[32 + g];
#pragma unroll
    for (int off = 16; off; off >>= 1) { vi += __shfl_xor(vi, off); vk += __shfl_xor(vk, off); }
    if (lane == 0) { p_i[i] = vi; p_k[i] = vk; }
}

// ---------------- final pairwise sigmoid ----------------
__global__ __launch_bounds__(256) void pred_kernel(const float* __restrict__ p_i,
                                                   const float* __restrict__ p_k,
                                                   float* __restrict__ out) {
    int tid = blockIdx.x * 256 + threadIdx.x;
    int i = tid / (M / 4);
    int k4 = (tid % (M / 4)) * 4;
    float pi = p_i[i];
    float4 pk = *(const float4*)&p_k[k4];
    float4 o;
    o.x = 1.f / (1.f + __expf(-(pi + pk.x)));
    o.y = 1.f / (1.f + __expf(-(pi + pk.y)));
    o.z = 1.f / (1.f + __expf(-(pi + pk.z)));
    o.w = 1.f / (1.f + __expf(-(pi + pk.w)));
    *(float4*)&out[(size_t)i * M + k4] = o;
}

extern "C" void kernel_launch(void* const* d_in, const int* in_sizes, int n_in,
                              void* d_out, int out_size, void* d_ws, size_t ws_size,
                              hipStream_t stream) {
    const float* h0    = (const float*)d_in[0];
    const int*   adj   = (const int*)d_in[1];
    const float* W1    = (const float*)d_in[2];
    const float* a1    = (const float*)d_in[3];
    const float* W2    = (const float*)d_in[4];
    const float* a2    = (const float*)d_in[5];
    const float* omega = (const float*)d_in[6];
    float* out = (float*)d_out;

    char* ws = (char*)d_ws;
    unsigned int*   packed = (unsigned int*)(ws + 0);        // 2 MB
    unsigned short* WhB1   = (unsigned short*)(ws + 2097152); // 512 KB
    unsigned short* WhB2   = (unsigned short*)(ws + 2621440); // 256 KB
    float* si1 = (float*)(ws + 2883584);
    float* sk1 = (float*)(ws + 2899968);
    float* cr1 = (float*)(ws + 2916352);
    float* si2 = (float*)(ws + 2932736);
    float* sk2 = (float*)(ws + 2949120);
    float* cr2 = (float*)(ws + 2965504);
    float* pi  = (float*)(ws + 2981888);
    float* pk  = (float*)(ws + 2998272);

    float* partial = out;          // d_out as split-K scratch (pred overwrites later)
    constexpr int KS = 16;

    pack_adj_kernel<<<(M * M) / 256, 256, 0, stream>>>(adj, packed);

    // layer 1 (F=64)
    fused_in_kernel<64, 64><<<M / 4, 256, 0, stream>>>(h0, W1, a1, WhB1, si1, sk1);
    rowsum_kernel<<<M / 4, 256, 0, stream>>>(si1, sk1, packed, cr1);
    attn_mfma_kernel<64, KS><<<(M / 64) * KS, 256, 0, stream>>>(WhB1, si1, cr1, packed, sk1, partial);

    // layer 2 (F=32), fused with layer-1 reduce
    fused_mid_kernel<KS><<<M / 4, 256, 0, stream>>>(partial, W2, a2, WhB2, si2, sk2);
    rowsum_kernel<<<M / 4, 256, 0, stream>>>(si2, sk2, packed, cr2);
    attn_mfma_kernel<32, KS><<<(M / 64) * KS, 256, 0, stream>>>(WhB2, si2, cr2, packed, sk2, partial);

    // link prediction
    fused_out_kernel<KS><<<M / 4, 256, 0, stream>>>(partial, omega, out + (size_t)M * M, pi, pk);
    pred_kernel<<<(M * M / 4) / 256, 256, 0, stream>>>(pi, pk, out);
}

// Round 6
// 95.622 us; speedup vs baseline: 4.3023x; 1.1597x over previous
//
#include <hip/hip_runtime.h>
#include <hip/hip_bf16.h>
#include <math.h>

#define M 4096
#define PWR 128            // packed words per row = 4096/32
#define ALPHA 0.2f
#define L2E 1.4426950408889634f

typedef __attribute__((ext_vector_type(8))) short bf16x8_t;   // 8 bf16 = 4 VGPRs
typedef __attribute__((ext_vector_type(4))) float f32x4_t;    // MFMA accumulator

#define EXP2F(x) __builtin_amdgcn_exp2f(x)   // v_exp_f32: 2^x
#define LOG2F(x) __builtin_amdgcn_logf(x)    // v_log_f32: log2(x)

// round-to-nearest-even float -> bf16 bits (cold paths)
__device__ inline unsigned short f2bf(float f) {
    unsigned int u = __float_as_uint(f);
    u = (u + 0x7fffu + ((u >> 16) & 1u)) >> 16;
    return (unsigned short)u;
}
// round-half-up float -> bf16 bits (hot path; p >= 0 finite)
__device__ inline unsigned short f2bf_fast(float f) {
    return (unsigned short)((__float_as_uint(f) + 0x8000u) >> 16);
}

// ---------------- fused: Wh1 = h0@W1 (registers), emit WhB1(bf16 frag layout), s_i, s_k ----
template <int DIN, int F>
__global__ __launch_bounds__(256) void fused_in_kernel(const float* __restrict__ h0,
                                                       const float* __restrict__ W,
                                                       const float* __restrict__ a,
                                                       unsigned short* __restrict__ WhB,
                                                       float* __restrict__ s_i,
                                                       float* __restrict__ s_k) {
    int wave = threadIdx.x >> 6, lane = threadIdx.x & 63;
    int i = blockIdx.x * 4 + wave;
    float acc = 0.f;                                   // Wh[i][lane]
#pragma unroll
    for (int j = 0; j < DIN; j++)
        acc += h0[(size_t)i * DIN + j] * W[j * F + lane];
    float vi = acc * a[lane], vk = acc * a[F + lane];
#pragma unroll
    for (int off = 32; off; off >>= 1) { vi += __shfl_xor(vi, off); vk += __shfl_xor(vk, off); }
    if (lane == 0) { s_i[i] = vi; s_k[i] = vk; }
    // scatter into B-fragment layout: [k5][fblk][lane(=kg*16+fl)][j]
    constexpr int NFB = F / 16;
    int fb = lane >> 4, fl = lane & 15;
    size_t idx = (((size_t)(i >> 5) * NFB + fb) * 64 + (((i & 31) >> 3) * 16 + fl)) * 8 + (i & 7);
    WhB[idx] = f2bf(acc);
}

// ---------------- prep: adj -> packed + packedT bits, plus layer-1 softmax denom ----------------
// block = 4 waves, one row per wave. crow in log2 domain: P = exp2(leaky*L2E + crow)
__global__ __launch_bounds__(256) void prep_kernel(const int* __restrict__ adj,
                                                   const float* __restrict__ s_i,
                                                   const float* __restrict__ s_k,
                                                   unsigned int* __restrict__ packed,
                                                   unsigned int* __restrict__ packedT,
                                                   float* __restrict__ crow) {
    __shared__ float sk_lds[M];                        // 16 KB
    __shared__ float wred[4];
    int tid = threadIdx.x;
    float lm = -INFINITY;
    for (int j = tid; j < M; j += 256) { float v = s_k[j]; sk_lds[j] = v; lm = fmaxf(lm, v); }
#pragma unroll
    for (int off = 32; off; off >>= 1) lm = fmaxf(lm, __shfl_xor(lm, off));
    if ((tid & 63) == 0) wred[tid >> 6] = lm;
    __syncthreads();
    float skmax = fmaxf(fmaxf(wred[0], wred[1]), fmaxf(wred[2], wred[3]));
    int wave = tid >> 6, lane = tid & 63;
    int i = blockIdx.x * 4 + wave;
    float si = s_i[i];
    float xm = si + skmax;
    float rl2 = fmaxf(xm, ALPHA * xm) * L2E;           // log2-domain upper bound on row max
    const int4* arow = (const int4*)(adj + (size_t)i * M);
    float sum = 0.f;
#pragma unroll 4
    for (int t = 0; t < 16; t++) {
        int4 av = arow[t * 64 + lane];                 // k0 = (t*64+lane)*4
        int k0 = (t * 64 + lane) * 4;
        unsigned int nib = (av.x > 0 ? 1u : 0u) | (av.y > 0 ? 2u : 0u) |
                           (av.z > 0 ? 4u : 0u) | (av.w > 0 ? 8u : 0u);
        float xs0 = sk_lds[k0], xs1 = sk_lds[k0 + 1], xs2 = sk_lds[k0 + 2], xs3 = sk_lds[k0 + 3];
        float xv[4] = { xs0, xs1, xs2, xs3 };
#pragma unroll
        for (int c = 0; c < 4; c++) {
            float x = si + xv[c];
            float e = fmaxf(x, ALPHA * x);
            float p = EXP2F(fmaf(e, L2E, -rl2));
            sum += ((nib >> c) & 1u) ? p : 0.f;
        }
        unsigned int sh = nib << ((lane & 7) * 4);
        sh |= __shfl_xor(sh, 1);
        sh |= __shfl_xor(sh, 2);
        sh |= __shfl_xor(sh, 4);
        if ((lane & 7) == 0) {
            int kw = k0 >> 5;                          // = t*8 + lane/8
            packed[(size_t)i * PWR + kw] = sh;
            packedT[(size_t)kw * M + i] = sh;
        }
    }
#pragma unroll
    for (int off = 32; off; off >>= 1) sum += __shfl_xor(sum, off);
    if (lane == 0) crow[i] = -rl2 - LOG2F(fmaxf(sum, 1e-37f));
}

// ---------------- layer-2 softmax denom (reads row-major packed, 2 MB) ----------------
__global__ __launch_bounds__(256) void rowsum_kernel(const float* __restrict__ s_i,
                                                     const float* __restrict__ s_k,
                                                     const unsigned int* __restrict__ packed,
                                                     float* __restrict__ crow) {
    __shared__ float sk_lds[M];
    __shared__ float wred[4];
    int tid = threadIdx.x;
    float lm = -INFINITY;
    for (int j = tid; j < M; j += 256) { float v = s_k[j]; sk_lds[j] = v; lm = fmaxf(lm, v); }
#pragma unroll
    for (int off = 32; off; off >>= 1) lm = fmaxf(lm, __shfl_xor(lm, off));
    if ((tid & 63) == 0) wred[tid >> 6] = lm;
    __syncthreads();
    float skmax = fmaxf(fmaxf(wred[0], wred[1]), fmaxf(wred[2], wred[3]));
    int wave = tid >> 6, lane = tid & 63;
    int i = blockIdx.x * 4 + wave;
    float si = s_i[i];
    float xm = si + skmax;
    float rl2 = fmaxf(xm, ALPHA * xm) * L2E;
    const unsigned int* prow = packed + (size_t)i * PWR;
    float sum = 0.f;
    for (int t = 0; t < M / 64; t++) {
        int k = lane + 64 * t;
        unsigned int bit = (prow[k >> 5] >> (k & 31)) & 1u;
        float x = si + sk_lds[k];
        float e = fmaxf(x, ALPHA * x);
        float p = EXP2F(fmaf(e, L2E, -rl2));
        sum += bit ? p : 0.f;
    }
#pragma unroll
    for (int off = 32; off; off >>= 1) sum += __shfl_xor(sum, off);
    if (lane == 0) crow[i] = -rl2 - LOG2F(fmaxf(sum, 1e-37f));
}

// ---------------- MFMA attention @ Wh: P generated in A-fragment registers ----------------
template <int F, int KSPLIT>
__global__ __launch_bounds__(256) void attn_mfma_kernel(const unsigned short* __restrict__ WhB,
                                                        const float* __restrict__ s_i,
                                                        const float* __restrict__ crow,
                                                        const unsigned int* __restrict__ packedT,
                                                        const float* __restrict__ s_k,
                                                        float* __restrict__ partial) {
    constexpr int NFB = F / 16;
    constexpr int KLEN = M / KSPLIT;
    constexpr int NRB = M / 64;
    int wave = threadIdx.x >> 6, lane = threadIdx.x & 63;
    int rb = blockIdx.x % NRB, ks = blockIdx.x / NRB;
    int R0 = rb * 64 + wave * 16;
    int row = R0 + (lane & 15);                        // A-operand row for this lane
    int kg = lane >> 4;                                // k-group 0..3
    float si = s_i[row], cr = crow[row];
    f32x4_t acc[NFB];
#pragma unroll
    for (int fb = 0; fb < NFB; fb++) acc[fb] = (f32x4_t)0.f;
    const int k_begin = ks * KLEN;
    for (int st = 0; st < KLEN / 32; st++) {
        int kb = k_begin + st * 32;
        float4 sa = *(const float4*)&s_k[kb + kg * 8];
        float4 sb = *(const float4*)&s_k[kb + kg * 8 + 4];
        unsigned int word = packedT[(size_t)(kb >> 5) * M + row];   // coalesced across lanes
        float sv[8] = { sa.x, sa.y, sa.z, sa.w, sb.x, sb.y, sb.z, sb.w };
        union { bf16x8_t v; unsigned short u[8]; } af;
#pragma unroll
        for (int j = 0; j < 8; j++) {
            float x = si + sv[j];
            float e = fmaxf(x, ALPHA * x);             // leakyrelu
            float p = EXP2F(fmaf(e, L2E, cr));         // softmax weight
            p = ((word >> (kg * 8 + j)) & 1u) ? p : 0.f;
            af.u[j] = f2bf_fast(p);
        }
        const unsigned short* bp = WhB + (size_t)(kb >> 5) * (NFB * 512) + (size_t)lane * 8;
#pragma unroll
        for (int fb = 0; fb < NFB; fb++) {
            bf16x8_t bfrag = *(const bf16x8_t*)(bp + (size_t)fb * 512);
            acc[fb] = __builtin_amdgcn_mfma_f32_16x16x32_bf16(af.v, bfrag, acc[fb], 0, 0, 0);
        }
    }
    // D layout: col = lane&15, row = (lane>>4)*4 + r
#pragma unroll
    for (int fb = 0; fb < NFB; fb++)
#pragma unroll
        for (int r = 0; r < 4; r++) {
            int ro = R0 + kg * 4 + r;
            partial[((size_t)ks * M + ro) * F + fb * 16 + (lane & 15)] = acc[fb][r];
        }
}

// ---------------- fused: reduce partial1 -> h1 (ELU, regs) -> Wh2, WhB2, s_i2, s_k2 ----
template <int KSPLIT>
__global__ __launch_bounds__(256) void fused_mid_kernel(const float* __restrict__ partial,
                                                        const float* __restrict__ W2,
                                                        const float* __restrict__ a2,
                                                        unsigned short* __restrict__ WhB2,
                                                        float* __restrict__ s_i2,
                                                        float* __restrict__ s_k2) {
    __shared__ float h_lds[4][64];
    int wave = threadIdx.x >> 6, lane = threadIdx.x & 63;
    int i = blockIdx.x * 4 + wave;
    float hv = 0.f;
#pragma unroll
    for (int ks = 0; ks < KSPLIT; ks++) hv += partial[((size_t)ks * M + i) * 64 + lane];
    hv = hv > 0.f ? hv : (__expf(hv) - 1.f);           // ELU -> h1[i][lane]
    h_lds[wave][lane] = hv;
    __syncthreads();
    int g = lane & 31, half = lane >> 5;
    float w2acc = 0.f;                                 // Wh2[i][g], split f-range by half
#pragma unroll
    for (int f = 0; f < 32; f++) {
        float hf = h_lds[wave][half * 32 + f];
        w2acc += hf * W2[(half * 32 + f) * 32 + g];
    }
    w2acc += __shfl_xor(w2acc, 32);
    float vi = w2acc * a2[g], vk = w2acc * a2[32 + g];
#pragma unroll
    for (int off = 16; off; off >>= 1) { vi += __shfl_xor(vi, off); vk += __shfl_xor(vk, off); }
    if (lane == 0) { s_i2[i] = vi; s_k2[i] = vk; }
    if (half == 0) {
        size_t idx = (((size_t)(i >> 5) * 2 + (g >> 4)) * 64 + (((i & 31) >> 3) * 16 + (g & 15))) * 8 + (i & 7);
        WhB2[idx] = f2bf(w2acc);
    }
}

// ---------------- fused: reduce partial2 -> hL (ELU) -> out tail + omega dots ----------------
template <int KSPLIT>
__global__ __launch_bounds__(256) void fused_out_kernel(const float* __restrict__ partial,
                                                        const float* __restrict__ omega,
                                                        float* __restrict__ hL_out,
                                                        float* __restrict__ p_i,
                                                        float* __restrict__ p_k) {
    int wave = threadIdx.x >> 6, lane = threadIdx.x & 63;
    int i = blockIdx.x * 4 + wave;
    int g = lane & 31, half = lane >> 5;
    float hv = 0.f;
#pragma unroll
    for (int h = 0; h < KSPLIT / 2; h++) {
        int ks = half * (KSPLIT / 2) + h;
        hv += partial[((size_t)ks * M + i) * 32 + g];
    }
    hv += __shfl_xor(hv, 32);
    hv = hv > 0.f ? hv : (__expf(hv) - 1.f);
    if (half == 0) hL_out[(size_t)i * 32 + g] = hv;
    float vi = hv * omega[g], vk = hv * omega[32 + g];
#pragma unroll
    for (int off = 16; off; off >>= 1) { vi += __shfl_xor(vi, off); vk += __shfl_xor(vk, off); }
    if (lane == 0) { p_i[i] = vi; p_k[i] = vk; }
}

// ---------------- final pairwise sigmoid ----------------
__global__ __launch_bounds__(256) void pred_kernel(const float* __restrict__ p_i,
                                                   const float* __restrict__ p_k,
                                                   float* __restrict__ out) {
    int tid = blockIdx.x * 256 + threadIdx.x;
    int i = tid / (M / 4);
    int k4 = (tid % (M / 4)) * 4;
    float pi = p_i[i];
    float4 pk = *(const float4*)&p_k[k4];
    float4 o;
    o.x = 1.f / (1.f + __expf(-(pi + pk.x)));
    o.y = 1.f / (1.f + __expf(-(pi + pk.y)));
    o.z = 1.f / (1.f + __expf(-(pi + pk.z)));
    o.w = 1.f / (1.f + __expf(-(pi + pk.w)));
    *(float4*)&out[(size_t)i * M + k4] = o;
}

extern "C" void kernel_launch(void* const* d_in, const int* in_sizes, int n_in,
                              void* d_out, int out_size, void* d_ws, size_t ws_size,
                              hipStream_t stream) {
    const float* h0    = (const float*)d_in[0];
    const int*   adj   = (const int*)d_in[1];
    const float* W1    = (const float*)d_in[2];
    const float* a1    = (const float*)d_in[3];
    const float* W2    = (const float*)d_in[4];
    const float* a2    = (const float*)d_in[5];
    const float* omega = (const float*)d_in[6];
    float* out = (float*)d_out;

    char* ws = (char*)d_ws;
    unsigned int*   packed  = (unsigned int*)(ws + 0);         // 2 MB (row-major)
    unsigned int*   packedT = (unsigned int*)(ws + 2097152);   // 2 MB (transposed)
    unsigned short* WhB1    = (unsigned short*)(ws + 4194304); // 512 KB
    unsigned short* WhB2    = (unsigned short*)(ws + 4718592); // 256 KB
    float* si1 = (float*)(ws + 4980736);
    float* sk1 = (float*)(ws + 4997120);
    float* cr1 = (float*)(ws + 5013504);
    float* si2 = (float*)(ws + 5029888);
    float* sk2 = (float*)(ws + 5046272);
    float* cr2 = (float*)(ws + 5062656);
    float* pi  = (float*)(ws + 5079040);
    float* pk  = (float*)(ws + 5095424);

    float* partial = out;          // d_out as split-K scratch (pred overwrites later)
    constexpr int KS = 16;

    // layer 1 (F=64)
    fused_in_kernel<64, 64><<<M / 4, 256, 0, stream>>>(h0, W1, a1, WhB1, si1, sk1);
    prep_kernel<<<M / 4, 256, 0, stream>>>(adj, si1, sk1, packed, packedT, cr1);
    attn_mfma_kernel<64, KS><<<(M / 64) * KS, 256, 0, stream>>>(WhB1, si1, cr1, packedT, sk1, partial);

    // layer 2 (F=32), fused with layer-1 reduce
    fused_mid_kernel<KS><<<M / 4, 256, 0, stream>>>(partial, W2, a2, WhB2, si2, sk2);
    rowsum_kernel<<<M / 4, 256, 0, stream>>>(si2, sk2, packed, cr2);
    attn_mfma_kernel<32, KS><<<(M / 64) * KS, 256, 0, stream>>>(WhB2, si2, cr2, packedT, sk2, partial);

    // link prediction
    fused_out_kernel<KS><<<M / 4, 256, 0, stream>>>(partial, omega, out + (size_t)M * M, pi, pk);
    pred_kernel<<<(M * M / 4) / 256, 256, 0, stream>>>(pi, pk, out);
}

// Round 7
// 71.441 us; speedup vs baseline: 5.7585x; 1.3385x over previous
//
#include <hip/hip_runtime.h>
#include <hip/hip_bf16.h>
#include <math.h>

#define M 4096
#define PWR 128            // packed words per row = 4096/32
#define ALPHA 0.2f
#define L2E 1.4426950408889634f

typedef __attribute__((ext_vector_type(8))) short bf16x8_t;   // 8 bf16 = 4 VGPRs
typedef __attribute__((ext_vector_type(4))) float f32x4_t;    // MFMA accumulator

#define EXP2F(x) __builtin_amdgcn_exp2f(x)   // v_exp_f32: 2^x
#define LOG2F(x) __builtin_amdgcn_logf(x)    // v_log_f32: log2(x)

// round-to-nearest-even float -> bf16 bits (cold paths)
__device__ inline unsigned short f2bf(float f) {
    unsigned int u = __float_as_uint(f);
    u = (u + 0x7fffu + ((u >> 16) & 1u)) >> 16;
    return (unsigned short)u;
}
// round-half-up float -> bf16 bits (hot path; p >= 0 finite)
__device__ inline unsigned short f2bf_fast(float f) {
    return (unsigned short)((__float_as_uint(f) + 0x8000u) >> 16);
}

// ---------------- fused: Wh1 = h0@W1, WhB1 frag scatter, s_i/s_k, AND adj bit-pack ----------
// block = 4 waves, one row per wave. Wh compute hides under the 64 MB adj stream.
template <int DIN, int F>
__global__ __launch_bounds__(256) void fused_in_kernel(const float* __restrict__ h0,
                                                       const float* __restrict__ W,
                                                       const float* __restrict__ a,
                                                       const int* __restrict__ adj,
                                                       unsigned short* __restrict__ WhB,
                                                       float* __restrict__ s_i,
                                                       float* __restrict__ s_k,
                                                       unsigned int* __restrict__ packedT) {
    int wave = threadIdx.x >> 6, lane = threadIdx.x & 63;
    int i = blockIdx.x * 4 + wave;
    float acc = 0.f;                                   // Wh[i][lane]
#pragma unroll
    for (int j = 0; j < DIN; j++)
        acc += h0[(size_t)i * DIN + j] * W[j * F + lane];
    float vi = acc * a[lane], vk = acc * a[F + lane];
#pragma unroll
    for (int off = 32; off; off >>= 1) { vi += __shfl_xor(vi, off); vk += __shfl_xor(vk, off); }
    if (lane == 0) { s_i[i] = vi; s_k[i] = vk; }
    // scatter into B-fragment layout: [k5][fblk][lane(=kg*16+fl)][j]
    constexpr int NFB = F / 16;
    int fb = lane >> 4, fl = lane & 15;
    size_t idx = (((size_t)(i >> 5) * NFB + fb) * 64 + (((i & 31) >> 3) * 16 + fl)) * 8 + (i & 7);
    WhB[idx] = f2bf(acc);
    // pack this row's adjacency into transposed bitmask
    const int4* arow = (const int4*)(adj + (size_t)i * M);
#pragma unroll 4
    for (int t = 0; t < 16; t++) {
        int4 av = arow[t * 64 + lane];                 // k0 = (t*64+lane)*4
        unsigned int nib = (av.x > 0 ? 1u : 0u) | (av.y > 0 ? 2u : 0u) |
                           (av.z > 0 ? 4u : 0u) | (av.w > 0 ? 8u : 0u);
        unsigned int sh = nib << ((lane & 7) * 4);
        sh |= __shfl_xor(sh, 1);
        sh |= __shfl_xor(sh, 2);
        sh |= __shfl_xor(sh, 4);
        if ((lane & 7) == 0) {
            int kw = t * 8 + (lane >> 3);              // word index along k
            packedT[(size_t)kw * M + i] = sh;
        }
    }
}

// ---------------- MFMA attention @ Wh with UNNORMALIZED P + row-sum side output ----------
// P_unnorm = exp2(leaky(si+sk)*L2E - rl2), rl2 = leaky(si+skmax)*L2E (block-computed,
// bitwise identical across blocks). partial[ks][row][F] and partialS[ks][row] emitted;
// normalization (1/S) is applied in the reduce kernels.
template <int F, int KSPLIT>
__global__ __launch_bounds__(256) void attn_mfma_kernel(const unsigned short* __restrict__ WhB,
                                                        const float* __restrict__ s_i,
                                                        const float* __restrict__ s_k,
                                                        const unsigned int* __restrict__ packedT,
                                                        float* __restrict__ partial,
                                                        float* __restrict__ partialS) {
    constexpr int NFB = F / 16;
    constexpr int KLEN = M / KSPLIT;
    constexpr int NRB = M / 64;
    __shared__ float wred[4];
    int tid = threadIdx.x, wave = tid >> 6, lane = tid & 63;
    // in-block global skmax (deterministic, identical in every block)
    float m = -INFINITY;
    for (int j = tid; j < M; j += 256) m = fmaxf(m, s_k[j]);
#pragma unroll
    for (int off = 32; off; off >>= 1) m = fmaxf(m, __shfl_xor(m, off));
    if (lane == 0) wred[wave] = m;
    __syncthreads();
    float skmax = fmaxf(fmaxf(wred[0], wred[1]), fmaxf(wred[2], wred[3]));

    int rb = blockIdx.x % NRB, ks = blockIdx.x / NRB;
    int R0 = rb * 64 + wave * 16;
    int row = R0 + (lane & 15);                        // A-operand row for this lane
    int kg = lane >> 4;                                // k-group 0..3
    float si = s_i[row];
    float xm = si + skmax;
    float rl2 = fmaxf(xm, ALPHA * xm) * L2E;           // log2-domain row-max bound
    f32x4_t acc[NFB];
#pragma unroll
    for (int fb = 0; fb < NFB; fb++) acc[fb] = (f32x4_t)0.f;
    float rsum = 0.f;
    const int k_begin = ks * KLEN;
    for (int st = 0; st < KLEN / 32; st++) {
        int kb = k_begin + st * 32;
        float4 sa = *(const float4*)&s_k[kb + kg * 8];
        float4 sb = *(const float4*)&s_k[kb + kg * 8 + 4];
        unsigned int word = packedT[(size_t)(kb >> 5) * M + row];   // coalesced across lanes
        float sv[8] = { sa.x, sa.y, sa.z, sa.w, sb.x, sb.y, sb.z, sb.w };
        union { bf16x8_t v; unsigned short u[8]; } af;
#pragma unroll
        for (int j = 0; j < 8; j++) {
            float x = si + sv[j];
            float e = fmaxf(x, ALPHA * x);             // leakyrelu
            float p = EXP2F(fmaf(e, L2E, -rl2));       // unnormalized weight <= 1
            p = ((word >> (kg * 8 + j)) & 1u) ? p : 0.f;
            rsum += p;
            af.u[j] = f2bf_fast(p);
        }
        const unsigned short* bp = WhB + (size_t)(kb >> 5) * (NFB * 512) + (size_t)lane * 8;
#pragma unroll
        for (int fb = 0; fb < NFB; fb++) {
            bf16x8_t bfrag = *(const bf16x8_t*)(bp + (size_t)fb * 512);
            acc[fb] = __builtin_amdgcn_mfma_f32_16x16x32_bf16(af.v, bfrag, acc[fb], 0, 0, 0);
        }
    }
    // row-sum: lanes {l, l+16, l+32, l+48} hold partials of row R0+l
    rsum += __shfl_xor(rsum, 16);
    rsum += __shfl_xor(rsum, 32);
    if (lane < 16) partialS[(size_t)ks * M + R0 + lane] = rsum;
    // D layout: col = lane&15, row = (lane>>4)*4 + r
#pragma unroll
    for (int fb = 0; fb < NFB; fb++)
#pragma unroll
        for (int r = 0; r < 4; r++) {
            int ro = R0 + kg * 4 + r;
            partial[((size_t)ks * M + ro) * F + fb * 16 + (lane & 15)] = acc[fb][r];
        }
}

// ---------------- fused: reduce partial1 -> normalize -> h1 (ELU) -> Wh2, WhB2, si2, sk2 ----
template <int KSPLIT>
__global__ __launch_bounds__(256) void fused_mid_kernel(const float* __restrict__ partial,
                                                        const float* __restrict__ partialS,
                                                        const float* __restrict__ W2,
                                                        const float* __restrict__ a2,
                                                        unsigned short* __restrict__ WhB2,
                                                        float* __restrict__ s_i2,
                                                        float* __restrict__ s_k2) {
    __shared__ float h_lds[4][64];
    int wave = threadIdx.x >> 6, lane = threadIdx.x & 63;
    int i = blockIdx.x * 4 + wave;
    float S = 0.f;
#pragma unroll
    for (int ks = 0; ks < KSPLIT; ks++) S += partialS[(size_t)ks * M + i];
    float rinv = S > 0.f ? 1.f / S : 0.f;
    float hv = 0.f;
#pragma unroll
    for (int ks = 0; ks < KSPLIT; ks++) hv += partial[((size_t)ks * M + i) * 64 + lane];
    hv *= rinv;
    hv = hv > 0.f ? hv : (__expf(hv) - 1.f);           // ELU -> h1[i][lane]
    h_lds[wave][lane] = hv;
    __syncthreads();
    int g = lane & 31, half = lane >> 5;
    float w2acc = 0.f;                                 // Wh2[i][g], split f-range by half
#pragma unroll
    for (int f = 0; f < 32; f++) {
        float hf = h_lds[wave][half * 32 + f];
        w2acc += hf * W2[(half * 32 + f) * 32 + g];
    }
    w2acc += __shfl_xor(w2acc, 32);
    float vi = w2acc * a2[g], vk = w2acc * a2[32 + g];
#pragma unroll
    for (int off = 16; off; off >>= 1) { vi += __shfl_xor(vi, off); vk += __shfl_xor(vk, off); }
    if (lane == 0) { s_i2[i] = vi; s_k2[i] = vk; }
    if (half == 0) {
        size_t idx = (((size_t)(i >> 5) * 2 + (g >> 4)) * 64 + (((i & 31) >> 3) * 16 + (g & 15))) * 8 + (i & 7);
        WhB2[idx] = f2bf(w2acc);
    }
}

// ---------------- fused: reduce partial2 -> normalize -> hL (ELU) -> out tail + omega dots ----
template <int KSPLIT>
__global__ __launch_bounds__(256) void fused_out_kernel(const float* __restrict__ partial,
                                                        const float* __restrict__ partialS,
                                                        const float* __restrict__ omega,
                                                        float* __restrict__ hL_out,
                                                        float* __restrict__ p_i,
                                                        float* __restrict__ p_k) {
    int wave = threadIdx.x >> 6, lane = threadIdx.x & 63;
    int i = blockIdx.x * 4 + wave;
    int g = lane & 31, half = lane >> 5;
    float S = 0.f;
#pragma unroll
    for (int ks = 0; ks < KSPLIT; ks++) S += partialS[(size_t)ks * M + i];
    float rinv = S > 0.f ? 1.f / S : 0.f;
    float hv = 0.f;
#pragma unroll
    for (int h = 0; h < KSPLIT / 2; h++) {
        int ks = half * (KSPLIT / 2) + h;
        hv += partial[((size_t)ks * M + i) * 32 + g];
    }
    hv += __shfl_xor(hv, 32);
    hv *= rinv;
    hv = hv > 0.f ? hv : (__expf(hv) - 1.f);
    if (half == 0) hL_out[(size_t)i * 32 + g] = hv;
    float vi = hv * omega[g], vk = hv * omega[32 + g];
#pragma unroll
    for (int off = 16; off; off >>= 1) { vi += __shfl_xor(vi, off); vk += __shfl_xor(vk, off); }
    if (lane == 0) { p_i[i] = vi; p_k[i] = vk; }
}

// ---------------- final pairwise sigmoid ----------------
__global__ __launch_bounds__(256) void pred_kernel(const float* __restrict__ p_i,
                                                   const float* __restrict__ p_k,
                                                   float* __restrict__ out) {
    int tid = blockIdx.x * 256 + threadIdx.x;
    int i = tid / (M / 4);
    int k4 = (tid % (M / 4)) * 4;
    float pi = p_i[i];
    float4 pk = *(const float4*)&p_k[k4];
    float4 o;
    o.x = 1.f / (1.f + __expf(-(pi + pk.x)));
    o.y = 1.f / (1.f + __expf(-(pi + pk.y)));
    o.z = 1.f / (1.f + __expf(-(pi + pk.z)));
    o.w = 1.f / (1.f + __expf(-(pi + pk.w)));
    *(float4*)&out[(size_t)i * M + k4] = o;
}

extern "C" void kernel_launch(void* const* d_in, const int* in_sizes, int n_in,
                              void* d_out, int out_size, void* d_ws, size_t ws_size,
                              hipStream_t stream) {
    const float* h0    = (const float*)d_in[0];
    const int*   adj   = (const int*)d_in[1];
    const float* W1    = (const float*)d_in[2];
    const float* a1    = (const float*)d_in[3];
    const float* W2    = (const float*)d_in[4];
    const float* a2    = (const float*)d_in[5];
    const float* omega = (const float*)d_in[6];
    float* out = (float*)d_out;

    char* ws = (char*)d_ws;
    unsigned int*   packedT = (unsigned int*)(ws + 0);         // 2 MB (transposed bits)
    unsigned short* WhB1    = (unsigned short*)(ws + 2097152); // 512 KB
    unsigned short* WhB2    = (unsigned short*)(ws + 2621440); // 256 KB
    float* si1 = (float*)(ws + 2883584);
    float* sk1 = (float*)(ws + 2899968);
    float* si2 = (float*)(ws + 2916352);
    float* sk2 = (float*)(ws + 2932736);
    float* pi  = (float*)(ws + 2949120);
    float* pk  = (float*)(ws + 2965504);
    float* pS1 = (float*)(ws + 2981888);   // KS*M*4 = 128 KB
    float* pS2 = (float*)(ws + 3112960);   // 128 KB

    float* partial = out;          // d_out as split-K scratch (pred overwrites later)
    constexpr int KS = 8;

    // layer 1 (F=64): Wh+svec+pack fused (compute hides under 64 MB adj stream)
    fused_in_kernel<64, 64><<<M / 4, 256, 0, stream>>>(h0, W1, a1, adj, WhB1, si1, sk1, packedT);
    attn_mfma_kernel<64, KS><<<(M / 64) * KS, 256, 0, stream>>>(WhB1, si1, sk1, packedT, partial, pS1);

    // layer 2 (F=32), fused with layer-1 normalize+reduce
    fused_mid_kernel<KS><<<M / 4, 256, 0, stream>>>(partial, pS1, W2, a2, WhB2, si2, sk2);
    attn_mfma_kernel<32, KS><<<(M / 64) * KS, 256, 0, stream>>>(WhB2, si2, sk2, packedT, partial, pS2);

    // link prediction
    fused_out_kernel<KS><<<M / 4, 256, 0, stream>>>(partial, pS2, omega, out + (size_t)M * M, pi, pk);
    pred_kernel<<<(M * M / 4) / 256, 256, 0, stream>>>(pi, pk, out);
}